// Round 1
// baseline (2880.141 us; speedup 1.0000x reference)
//
#include <hip/hip_runtime.h>

#define N_GRAPHS_C 256

// Edge kernel: all per-edge math in (Angstrom, electron-charge, eV) units so
// fp32 intermediates stay ~O(1..100) instead of ~1e-38 (reference multiplies
// by e=1.6e-19 first, which would denormalize q*q in fp32).
//   pref_eV = KEV * q1*q2 / r_A            (KEV = k_e e^2 / (1 A) in eV = 14.3996)
//   ecoul_eV = pref*(0.5*damp + erfc - 1)
//   fij_eV_per_A = dij_A * pref * (damp + erfc + 2*g*r*exp(-(g r)^2) - 1) / r^2
__global__ __launch_bounds__(256) void edge_kernel(
    const float* __restrict__ dij, const float* __restrict__ q,
    const float* __restrict__ g_ewald,
    const int* __restrict__ row, const int* __restrict__ col,
    float* __restrict__ e_atom, float* __restrict__ force,
    int n_edges)
{
    int e = blockIdx.x * blockDim.x + threadIdx.x;
    if (e >= n_edges) return;

    const float gA = g_ewald[0] * 1e-10f;   // 1/m -> 1/Angstrom
    const float KEV = (float)(8987551792.3 * 1.602176634e-9); // 14.399645...

    float dx = dij[3 * e + 0];
    float dy = dij[3 * e + 1];
    float dz = dij[3 * e + 2];
    int r = row[e];
    int c = col[e];
    float qr = q[r];
    float qc = q[c];

    float r2 = dx * dx + dy * dy + dz * dz;
    float inv_r = rsqrtf(r2);
    float rA = r2 * inv_r;                  // |dij| in Angstrom

    float pref = KEV * qr * qc * inv_r;     // eV

    float damp = 1.0f;
    if (rA < 2.2f)
        damp = __expf(-18.7f * (2.2f - rA) * (1.0f / 2.2f));

    float grij = gA * rA;
    float expm2 = __expf(-grij * grij);
    float t = 1.0f / (1.0f + 0.3275911f * grij);
    float erfc = t * (0.254829592f +
                 t * (-0.284496736f +
                 t * (1.421413741f +
                 t * (-1.453152027f +
                 t * 1.061405429f)))) * expm2;

    float ecoul = pref * (0.5f * damp + (erfc - 1.0f));          // eV
    float S = damp + erfc + 2.0f * grij * expm2 - 1.0f;
    float fs = pref * S * (inv_r * inv_r);                       // eV/A^2
    float fx = dx * fs, fy = dy * fs, fz = dz * fs;              // eV/A

    atomicAdd(&e_atom[r], ecoul);
    atomicAdd(&force[3 * r + 0], fx);
    atomicAdd(&force[3 * r + 1], fy);
    atomicAdd(&force[3 * r + 2], fz);
    atomicAdd(&force[3 * c + 0], -fx);
    atomicAdd(&force[3 * c + 1], -fy);
    atomicAdd(&force[3 * c + 2], -fz);
}

// Atom -> graph energy. batch is sorted, so almost every wave is
// batch-uniform: ballot-check, shuffle-reduce, one atomic per wave.
__global__ __launch_bounds__(256) void atom_kernel(
    const float* __restrict__ e_atom, const int* __restrict__ batch,
    float* __restrict__ energy, int n_atoms)
{
    int i = blockIdx.x * blockDim.x + threadIdx.x;
    int ic = i < n_atoms ? i : (n_atoms - 1);
    float v = (i < n_atoms) ? e_atom[ic] : 0.0f;
    int b = batch[ic];

    int b0 = __shfl(b, 0, 64);
    unsigned long long m = __ballot(b == b0);
    if (m == ~0ull) {
        for (int off = 32; off > 0; off >>= 1)
            v += __shfl_down(v, off, 64);
        if ((threadIdx.x & 63) == 0)
            atomicAdd(&energy[b], v);
    } else {
        atomicAdd(&energy[b], v);
    }
}

extern "C" void kernel_launch(void* const* d_in, const int* in_sizes, int n_in,
                              void* d_out, int out_size, void* d_ws, size_t ws_size,
                              hipStream_t stream) {
    const float* dij      = (const float*)d_in[0];
    const float* q        = (const float*)d_in[1];
    const float* g_ewald  = (const float*)d_in[2];
    const int*   row      = (const int*)d_in[3];
    const int*   col      = (const int*)d_in[4];
    const int*   batch    = (const int*)d_in[5];

    int n_edges = in_sizes[0] / 3;
    int n_atoms = in_sizes[1];

    float* energy = (float*)d_out;               // [256]
    float* force  = (float*)d_out + N_GRAPHS_C;  // [n_atoms*3]
    float* e_atom = (float*)d_ws;                // [n_atoms]

    // Harness poisons d_out/d_ws with 0xAA before every timed launch.
    hipMemsetAsync(d_out, 0, (size_t)out_size * sizeof(float), stream);
    hipMemsetAsync(d_ws, 0, (size_t)n_atoms * sizeof(float), stream);

    int threads = 256;
    int eblocks = (n_edges + threads - 1) / threads;
    edge_kernel<<<eblocks, threads, 0, stream>>>(
        dij, q, g_ewald, row, col, e_atom, force, n_edges);

    int ablocks = (n_atoms + threads - 1) / threads;
    atom_kernel<<<ablocks, threads, 0, stream>>>(
        e_atom, batch, energy, n_atoms);
}